// Round 16
// baseline (201.954 us; speedup 1.0000x reference)
//
#include <hip/hip_runtime.h>
#include <cstdint>
#include <cstddef>

// ---------------------------------------------------------------------------
// MultiHeadAttention block, MI355X/gfx950.  Round 16.
// B=4, S=1024, D=1024, H=16, DK=DV=64.  Outputs (out[B,S,D], attn[B,H,S,S]) fp32.
// R16 = R15 (passing, 195.8us) + T5 s_setprio(1) around attn MFMA clusters
// (zero-risk scheduler hint; guide m191: +4-7% on attn with wave role
// diversity).  Everything else R15-exact.
// ---------------------------------------------------------------------------

typedef __attribute__((ext_vector_type(8))) short short8;   // 8 x bf16 (4 VGPR)
typedef __attribute__((ext_vector_type(4))) short short4v;  // 8B vector
typedef __attribute__((ext_vector_type(4))) float f32x4;    // MFMA accum

typedef __attribute__((address_space(1))) void gl_void;
typedef __attribute__((address_space(3))) void lds_void;

#define MFMA16(a, b, c) __builtin_amdgcn_mfma_f32_16x16x32_bf16(a, b, c, 0, 0, 0)
#define GLL(src, dst) __builtin_amdgcn_global_load_lds((gl_void*)(src), (lds_void*)(dst), 16, 0, 0)
#define SBAR() __builtin_amdgcn_s_barrier()
// counted wait, memory clobber only (no sched_barrier: R6 regression)
#define WAIT_VM(n) asm volatile("s_waitcnt vmcnt(" #n ")" ::: "memory")

__device__ __forceinline__ unsigned short f2bf(float f) {
  union { float f; unsigned u; } v; v.f = f;
  unsigned r = v.u + 0x7FFFu + ((v.u >> 16) & 1u);  // RNE
  return (unsigned short)(r >> 16);
}
__device__ __forceinline__ float bf2f(unsigned short h) {
  union { unsigned u; float f; } v; v.u = ((unsigned)h) << 16;
  return v.f;
}

// ---------------------------------------------------------------------------
// K0: transpose-convert 1024x1024 fp32 W -> bf16 W^T (N x K), z selects W
// ---------------------------------------------------------------------------
__global__ __launch_bounds__(256) void transpose_w(
    const float* __restrict__ wq, const float* __restrict__ wk,
    const float* __restrict__ wv, const float* __restrict__ wo,
    unsigned short* __restrict__ wt) {
  __shared__ unsigned short tile[64][68];
  const int z = blockIdx.z;
  const float* W = (z == 0) ? wq : (z == 1) ? wk : (z == 2) ? wv : wo;
  unsigned short* out = wt + (size_t)z * 1048576;
  const int n0 = blockIdx.x * 64, k0 = blockIdx.y * 64;
  const int tr = threadIdx.x >> 4;
  const int tc = (threadIdx.x & 15) * 4;
#pragma unroll
  for (int i = 0; i < 4; ++i) {
    int k = tr + i * 16;
    float4 x = *reinterpret_cast<const float4*>(W + (size_t)(k0 + k) * 1024 + n0 + tc);
    tile[k][tc + 0] = f2bf(x.x); tile[k][tc + 1] = f2bf(x.y);
    tile[k][tc + 2] = f2bf(x.z); tile[k][tc + 3] = f2bf(x.w);
  }
  __syncthreads();
#pragma unroll
  for (int i = 0; i < 4; ++i) {
    int n = tr + i * 16;
    short4v o;
    o[0] = (short)tile[tc + 0][n]; o[1] = (short)tile[tc + 1][n];
    o[2] = (short)tile[tc + 2][n]; o[3] = (short)tile[tc + 3][n];
    *reinterpret_cast<short4v*>(out + (size_t)(n0 + n) * 1024 + k0 + tc) = o;
  }
}

// ---------------------------------------------------------------------------
// K1: fused QKV projection GEMM, R4 2-phase structure (__syncthreads).
// z==0: q=(acc+bias)*0.125*log2e -> qb ; z==1: +pos_k -> kb ;
// z==2: +pos_v -> vP key-tiled [bh][s>>3][dv][s&7].
// ---------------------------------------------------------------------------
__global__ __launch_bounds__(256) void gemm_qkv(
    const float* __restrict__ Qf, const float* __restrict__ Kf,
    const float* __restrict__ Vf, const unsigned short* __restrict__ wt,
    const float* __restrict__ bq, const float* __restrict__ bk,
    const float* __restrict__ bv, const float* __restrict__ pos_k,
    const float* __restrict__ pos_v, unsigned short* __restrict__ qb,
    unsigned short* __restrict__ kbuf, unsigned short* __restrict__ vP) {
  __shared__ unsigned short lds[16384];  // A dbuf [0,16K) | B dbuf [16K,32K)
  const int z = blockIdx.z;
  const float* A = (z == 0) ? Qf : (z == 1) ? Kf : Vf;
  const unsigned short* Bt = wt + (size_t)z * 1048576;
  const float* bias = (z == 0) ? bq : (z == 1) ? bk : bv;

  const int tid = threadIdx.x;
  const int lane = tid & 63;
  const int w = tid >> 6;
  const int g = lane >> 4;
  const int lr = lane & 15;
  const int wg = blockIdx.y * 8 + blockIdx.x;
  const int lg = (wg & 7) * 32 + (wg >> 3);
  const int m0 = (lg >> 3) << 7;
  const int n0 = (lg & 7) << 7;
  const int wm = w >> 1, wn = w & 1;

  const int ra0 = tid >> 2, ca = tid & 3;
  const int ra1 = ra0 + 64;
  const int wA0 = ra0 * 64 + ((ca ^ ((ra0 >> 1) & 3)) << 4);
  const int wA1 = ra1 * 64 + ((ca ^ ((ra1 >> 1) & 3)) << 4);
  const float* a0p = A + (size_t)(m0 + ra0) * 1024 + ca * 8;
  const float* a1p = A + (size_t)(m0 + ra1) * 1024 + ca * 8;

  const int c0 = (w << 6) + lane;
  const int r0 = c0 >> 2;
  const int sl0 = (c0 & 3) ^ ((r0 >> 1) & 3);
  const int c1 = c0 + 256;
  const int r1 = c1 >> 2;
  const int sl1 = (c1 & 3) ^ ((r1 >> 1) & 3);
  const size_t gb0 = ((size_t)(n0 + r0) << 10) + (sl0 << 3);
  const size_t gb1 = ((size_t)(n0 + r1) << 10) + (sl1 << 3);
  char* ldsc = (char*)lds;

  int offA[4], offB[4];
#pragma unroll
  for (int i = 0; i < 4; ++i) {
    int rt = (wm << 6) + (i << 4) + lr;
    offA[i] = rt * 64 + ((g ^ ((rt >> 1) & 3)) << 4);
    int nt = (wn << 6) + (i << 4) + lr;
    offB[i] = nt * 64 + ((g ^ ((nt >> 1) & 3)) << 4);
  }

  f32x4 acc[4][4] = {};

  // prologue: stage kt=0 into buffer 0
  {
    const float4 fa = *reinterpret_cast<const float4*>(a0p);
    const float4 fb = *reinterpret_cast<const float4*>(a0p + 4);
    const float4 fc = *reinterpret_cast<const float4*>(a1p);
    const float4 fd = *reinterpret_cast<const float4*>(a1p + 4);
    short8 pa, pb;
    pa[0] = (short)f2bf(fa.x); pa[1] = (short)f2bf(fa.y);
    pa[2] = (short)f2bf(fa.z); pa[3] = (short)f2bf(fa.w);
    pa[4] = (short)f2bf(fb.x); pa[5] = (short)f2bf(fb.y);
    pa[6] = (short)f2bf(fb.z); pa[7] = (short)f2bf(fb.w);
    pb[0] = (short)f2bf(fc.x); pb[1] = (short)f2bf(fc.y);
    pb[2] = (short)f2bf(fc.z); pb[3] = (short)f2bf(fc.w);
    pb[4] = (short)f2bf(fd.x); pb[5] = (short)f2bf(fd.y);
    pb[6] = (short)f2bf(fd.z); pb[7] = (short)f2bf(fd.w);
    *reinterpret_cast<short8*>(ldsc + wA0) = pa;
    *reinterpret_cast<short8*>(ldsc + wA1) = pb;
    __builtin_amdgcn_global_load_lds((gl_void*)(Bt + gb0),
                                     (lds_void*)(ldsc + 16384 + (w << 10)), 16, 0, 0);
    __builtin_amdgcn_global_load_lds((gl_void*)(Bt + gb1),
                                     (lds_void*)(ldsc + 16384 + 4096 + (w << 10)), 16, 0, 0);
    __syncthreads();
  }

  for (int kt = 0; kt < 32; ++kt) {
    const int cur = (kt & 1) << 13;
    const int nxt = ((kt + 1) & 1) << 13;
    float4 fa, fb, fc, fd;
    if (kt < 31) {
      const int kb32 = (kt + 1) << 5;
      __builtin_amdgcn_global_load_lds((gl_void*)(Bt + gb0 + kb32),
                                       (lds_void*)(ldsc + 16384 + nxt + (w << 10)), 16, 0, 0);
      __builtin_amdgcn_global_load_lds((gl_void*)(Bt + gb1 + kb32),
                                       (lds_void*)(ldsc + 16384 + nxt + 4096 + (w << 10)), 16, 0, 0);
      fa = *reinterpret_cast<const float4*>(a0p + kb32);
      fb = *reinterpret_cast<const float4*>(a0p + kb32 + 4);
      fc = *reinterpret_cast<const float4*>(a1p + kb32);
      fd = *reinterpret_cast<const float4*>(a1p + kb32 + 4);
    }
    short8 am[4], bn[4];
#pragma unroll
    for (int i = 0; i < 4; ++i) {
      am[i] = *reinterpret_cast<const short8*>(ldsc + cur + offA[i]);
      bn[i] = *reinterpret_cast<const short8*>(ldsc + 16384 + cur + offB[i]);
    }
#pragma unroll
    for (int i = 0; i < 4; ++i)
#pragma unroll
      for (int j = 0; j < 4; ++j)
        acc[i][j] = MFMA16(am[i], bn[j], acc[i][j]);
    if (kt < 31) {
      short8 pa, pb;
      pa[0] = (short)f2bf(fa.x); pa[1] = (short)f2bf(fa.y);
      pa[2] = (short)f2bf(fa.z); pa[3] = (short)f2bf(fa.w);
      pa[4] = (short)f2bf(fb.x); pa[5] = (short)f2bf(fb.y);
      pa[6] = (short)f2bf(fb.z); pa[7] = (short)f2bf(fb.w);
      pb[0] = (short)f2bf(fc.x); pb[1] = (short)f2bf(fc.y);
      pb[2] = (short)f2bf(fc.z); pb[3] = (short)f2bf(fc.w);
      pb[4] = (short)f2bf(fd.x); pb[5] = (short)f2bf(fd.y);
      pb[6] = (short)f2bf(fd.z); pb[7] = (short)f2bf(fd.w);
      *reinterpret_cast<short8*>(ldsc + nxt + wA0) = pa;
      *reinterpret_cast<short8*>(ldsc + nxt + wA1) = pb;
    }
    __syncthreads();
  }

#pragma unroll
  for (int i = 0; i < 4; ++i) {
#pragma unroll
    for (int j = 0; j < 4; ++j) {
      const int n = n0 + (wn << 6) + (j << 4) + lr;
      const int hh = n >> 6, dk = n & 63;
      const float bs = bias[n];
      const int mb = m0 + (wm << 6) + (i << 4) + (g << 2);
      const int b = mb >> 10, s0 = mb & 1023;
      if (z == 2) {
        short4v o;
#pragma unroll
        for (int r = 0; r < 4; ++r) {
          const float val = acc[i][j][r] + bs +
                            pos_v[((((size_t)hh << 10) + s0 + r) << 6) + dk];
          o[r] = (short)f2bf(val);
        }
        // vP[bh][s>>3][dv][s&7]: elem off = (s>>3)*512 + dv*8 + (s&7).
        *reinterpret_cast<short4v*>(
            vP + ((size_t)(b * 16 + hh) << 16) + ((s0 >> 3) << 9) + (dk << 3) +
            (s0 & 7)) = o;
      } else {
#pragma unroll
        for (int r = 0; r < 4; ++r) {
          float val = acc[i][j][r];
          if (z == 0) {
            val = (val + bs) * 0.180336880111f;  // 0.125 * log2(e): exp2 fold
          } else {
            val = val + bs + pos_k[((((size_t)hh << 10) + s0 + r) << 6) + dk];
          }
          unsigned short* dst = (z == 0) ? qb : kbuf;
          dst[((((size_t)(b * 16 + hh) << 10) + s0 + r) << 6) + dk] = f2bf(val);
        }
      }
    }
  }
}

// ---------------------------------------------------------------------------
// K2: FUSED attention — R10-exact structure + T5 setprio around MFMA.
// 4 waves x 16 q-rows, grid 1024 (XCD-swizzled).  LDS 24KB.
// pass0 vmcnt: K(ct+1)[2 glls] -> vmcnt(2); tail 0.
// pass1 vmcnt: ct=0 -> 2, steady -> 12, ct=15 -> 10.
// ---------------------------------------------------------------------------
__global__ __launch_bounds__(256) void attn_fused(
    const unsigned short* __restrict__ qb,
    const unsigned short* __restrict__ kb,
    const unsigned short* __restrict__ vP,
    unsigned short* __restrict__ ctxb,
    float* __restrict__ attn_out) {
  __shared__ char smem[24576];  // K dbuf 16K | p-tiles 4 x 2K
  const int tid = threadIdx.x;
  const int lane = tid & 63;
  const int w = tid >> 6;
  const int g = lane >> 4;
  const int lr = lane & 15;
  const int wg = ((blockIdx.x & 7) << 7) + (blockIdx.x >> 3);
  const int bh = wg >> 4, qt = wg & 15;
  const int b = bh >> 4, h = bh & 15;
  const int qrow0 = (qt << 6) + (w << 4);
  const size_t headoff = (size_t)bh << 16;

  const size_t qoff = headoff + (size_t)(qrow0 + lr) * 64 + (g << 3);
  const short8 a0 = *reinterpret_cast<const short8*>(qb + qoff);
  const short8 a1 = *reinterpret_cast<const short8*>(qb + qoff + 32);

  const int key0 = tid >> 3, sl0 = (tid & 7) ^ (key0 & 7);
  const int key1 = 32 + (tid >> 3), sl1 = (tid & 7) ^ (key1 & 7);
  const unsigned short* ks0 = kb + headoff + (size_t)key0 * 64 + (sl0 << 3);
  const unsigned short* ks1 = kb + headoff + (size_t)key1 * 64 + (sl1 << 3);

  // ================= pass 0: row sums =================
  GLL(ks0, smem + (w << 10));                   // K(0) -> b0
  GLL(ks1, smem + 4096 + (w << 10));
  GLL(ks0 + 4096, smem + 8192 + (w << 10));     // K(1) -> b1
  GLL(ks1 + 4096, smem + 8192 + 4096 + (w << 10));

  float l[4] = {0.f, 0.f, 0.f, 0.f};
  for (int ct = 0; ct < 16; ++ct) {
    if (ct < 15) { WAIT_VM(2); } else { WAIT_VM(0); }
    SBAR();
    const char* kl = smem + ((ct & 1) << 13);
    __builtin_amdgcn_s_setprio(1);
#pragma unroll
    for (int kf = 0; kf < 4; ++kf) {
      const int kr = (kf << 4) + lr;
      const char* row = kl + (kr << 7);
      const short8 b0 = *reinterpret_cast<const short8*>(row + ((g ^ (kr & 7)) << 4));
      const short8 b1 = *reinterpret_cast<const short8*>(row + (((4 + g) ^ (kr & 7)) << 4));
      f32x4 acc = {0.f, 0.f, 0.f, 0.f};
      acc = MFMA16(a0, b0, acc);
      acc = MFMA16(a1, b1, acc);
#pragma unroll
      for (int r = 0; r < 4; ++r) l[r] += exp2f(acc[r]);
    }
    __builtin_amdgcn_s_setprio(0);
    SBAR();
    if (ct + 2 < 16) {
      const int koff = (ct + 2) << 12;
      const int bo = (ct & 1) << 13;
      GLL(ks0 + koff, smem + bo + (w << 10));
      GLL(ks1 + koff, smem + bo + 4096 + (w << 10));
    }
  }
#pragma unroll
  for (int r = 0; r < 4; ++r) {
    l[r] += __shfl_xor(l[r], 1);
    l[r] += __shfl_xor(l[r], 2);
    l[r] += __shfl_xor(l[r], 4);
    l[r] += __shfl_xor(l[r], 8);
  }
  float inv[4];
#pragma unroll
  for (int r = 0; r < 4; ++r) inv[r] = 1.0f / l[r];

  // ================= pass 1: normalized PV + attn write =================
  GLL(ks0, smem + (w << 10));                           // K(0) -> buf0
  GLL(ks1, smem + 4096 + (w << 10));
  GLL(ks0 + 4096, smem + 8192 + (w << 10));             // K(1) -> buf1
  GLL(ks1 + 4096, smem + 8192 + 4096 + (w << 10));

  char* ew = smem + 16384 + (w << 11);  // per-wave 16 x 64 bf16 p-tile
  float* ab = attn_out + ((size_t)bh << 20);
  f32x4 ctx[4] = {};

  for (int ct = 0; ct < 16; ++ct) {
    if (ct == 0) { WAIT_VM(2); }
    else if (ct == 15) { WAIT_VM(10); }
    else { WAIT_VM(12); }
    SBAR();
    const int cur = (ct & 1) << 13;
    const int kc0 = ct << 6;
    const char* kl = smem + cur;

    // QK -> p (normalized, bf16 into wave-private swizzled tile)
    __builtin_amdgcn_s_setprio(1);
#pragma unroll
    for (int kf = 0; kf < 4; ++kf) {
      const int kr = (kf << 4) + lr;
      const char* row = kl + (kr << 7);
      const short8 b0 = *reinterpret_cast<const short8*>(row + ((g ^ (kr & 7)) << 4));
      const short8 b1 = *reinterpret_cast<const short8*>(row + (((4 + g) ^ (kr & 7)) << 4));
      f32x4 acc = {0.f, 0.f, 0.f, 0.f};
      acc = MFMA16(a0, b0, acc);
      acc = MFMA16(a1, b1, acc);
#pragma unroll
      for (int r = 0; r < 4; ++r) {
        const float p = exp2f(acc[r]) * inv[r];
        const int prow = (g << 2) + r;
        const int kc = (kf << 4) + lr;
        *(unsigned short*)(ew + (prow << 7) + ((((kc >> 3) ^ (prow & 7))) << 4) +
                           ((kc & 7) << 1)) = f2bf(p);
      }
    }
    __builtin_amdgcn_s_setprio(0);

    // normalized attn chunk write: wave's 16 rows x 64 keys fp32 (R10-exact)
#pragma unroll
    for (int p2 = 0; p2 < 2; ++p2) {
      const int row = lane >> 2;
      const int s = (lane & 3) + (p2 << 2);
      const short8 pv = *reinterpret_cast<const short8*>(
          ew + (row << 7) + ((s ^ (row & 7)) << 4));
      float* dst = ab + ((size_t)(qrow0 + row) << 10) + kc0 + (s << 3);
      float4 o0, o1;
      o0.x = bf2f((unsigned short)pv[0]); o0.y = bf2f((unsigned short)pv[1]);
      o0.z = bf2f((unsigned short)pv[2]); o0.w = bf2f((unsigned short)pv[3]);
      o1.x = bf2f((unsigned short)pv[4]); o1.y = bf2f((unsigned short)pv[5]);
      o1.z = bf2f((unsigned short)pv[6]); o1.w = bf2f((unsigned short)pv[7]);
      *reinterpret_cast<float4*>(dst) = o0;
      *reinterpret_cast<float4*>(dst + 4) = o1;
    }

    // PV with direct V loads from key-tiled vP (L2-resident)
    const short8 pa0 = *reinterpret_cast<const short8*>(
        ew + (lr << 7) + ((g ^ (lr & 7)) << 4));
    const short8 pa1 = *reinterpret_cast<const short8*>(
        ew + (lr << 7) + (((4 + g) ^ (lr & 7)) << 4));
    const unsigned short* vch0 = vP + headoff + ((size_t)((kc0 >> 3) + g) << 9);
    const unsigned short* vch1 = vch0 + (4 << 9);
    __builtin_amdgcn_s_setprio(1);
#pragma unroll
    for (int dt = 0; dt < 4; ++dt) {
      const int dv = (dt << 4) + lr;
      const short8 v0 = *reinterpret_cast<const short8*>(vch0 + (dv << 3));
      const short8 v1 = *reinterpret_cast<const short8*>(vch1 + (dv << 3));
      ctx[dt] = MFMA16(pa0, v0, ctx[dt]);
      ctx[dt] = MFMA16(pa1, v1, ctx[dt]);
    }
    __builtin_amdgcn_s_setprio(0);
    SBAR();
    if (ct + 2 < 16) {
      const int kn = (ct + 2) << 6;
      const int bo = (ct & 1) << 13;
      GLL(ks0 + ((size_t)kn << 6), smem + bo + (w << 10));
      GLL(ks1 + ((size_t)kn << 6), smem + bo + 4096 + (w << 10));
    }
  }

  // ctx write (already normalized), layout [b*S+s][h*64+dv]
#pragma unroll
  for (int dt = 0; dt < 4; ++dt) {
#pragma unroll
    for (int r = 0; r < 4; ++r) {
      const int srow = qrow0 + (g << 2) + r;
      const int n = (h << 6) + (dt << 4) + lr;
      ctxb[((((size_t)(b << 10)) + srow) << 10) + n] = f2bf(ctx[dt][r]);
    }
  }
}

// ---------------------------------------------------------------------------
// K3: out-projection GEMM, R4 2-phase structure (__syncthreads).
// ---------------------------------------------------------------------------
__global__ __launch_bounds__(256) void gemm_out(
    const unsigned short* __restrict__ A, const unsigned short* __restrict__ Bt,
    const float* __restrict__ bias, const float* __restrict__ resid,
    float* __restrict__ outf) {
  __shared__ unsigned short lds[16384];
  const int tid = threadIdx.x;
  const int lane = tid & 63;
  const int w = tid >> 6;
  const int g = lane >> 4;
  const int lr = lane & 15;
  const int wg = blockIdx.y * 8 + blockIdx.x;
  const int lg = (wg & 7) * 32 + (wg >> 3);
  const int m0 = (lg >> 3) << 7;
  const int n0 = (lg & 7) << 7;
  const int wm = w >> 1, wn = w & 1;

  const int c0 = (w << 6) + lane;
  const int r0 = c0 >> 2;
  const int sl0 = (c0 & 3) ^ ((r0 >> 1) & 3);
  const int c1 = c0 + 256;
  const int r1 = c1 >> 2;
  const int sl1 = (c1 & 3) ^ ((r1 >> 1) & 3);

  const size_t ga0 = ((size_t)(m0 + r0) << 10) + (sl0 << 3);
  const size_t ga1 = ((size_t)(m0 + r1) << 10) + (sl1 << 3);
  const size_t gb0 = ((size_t)(n0 + r0) << 10) + (sl0 << 3);
  const size_t gb1 = ((size_t)(n0 + r1) << 10) + (sl1 << 3);

  char* ldsc = (char*)lds;

  int offA[4], offB[4];
#pragma unroll
  for (int i = 0; i < 4; ++i) {
    int rt = (wm << 6) + (i << 4) + lr;
    offA[i] = rt * 64 + ((g ^ ((rt >> 1) & 3)) << 4);
    int nt = (wn << 6) + (i << 4) + lr;
    offB[i] = nt * 64 + ((g ^ ((nt >> 1) & 3)) << 4);
  }

  // prologue: stage kt=0 into buffer 0
  GLL(A + ga0, ldsc + (w << 10));
  GLL(A + ga1, ldsc + 4096 + (w << 10));
  GLL(Bt + gb0, ldsc + 16384 + (w << 10));
  GLL(Bt + gb1, ldsc + 16384 + 4096 + (w << 10));
  __syncthreads();

  f32x4 acc[4][4] = {};
  for (int kt = 0; kt < 32; ++kt) {
    const int cur = (kt & 1) << 13;
    if (kt < 31) {
      const int nxt = ((kt + 1) & 1) << 13;
      const int kb32 = (kt + 1) << 5;
      GLL(A + ga0 + kb32, ldsc + nxt + (w << 10));
      GLL(A + ga1 + kb32, ldsc + nxt + 4096 + (w << 10));
      GLL(Bt + gb0 + kb32, ldsc + 16384 + nxt + (w << 10));
      GLL(Bt + gb1 + kb32, ldsc + 16384 + nxt + 4096 + (w << 10));
    }
    short8 am[4], bn[4];
#pragma unroll
    for (int i = 0; i < 4; ++i) {
      am[i] = *reinterpret_cast<const short8*>(ldsc + cur + offA[i]);
      bn[i] = *reinterpret_cast<const short8*>(ldsc + 16384 + cur + offB[i]);
    }
#pragma unroll
    for (int i = 0; i < 4; ++i)
#pragma unroll
      for (int j = 0; j < 4; ++j)
        acc[i][j] = MFMA16(am[i], bn[j], acc[i][j]);
    __syncthreads();
  }

#pragma unroll
  for (int i = 0; i < 4; ++i) {
#pragma unroll
    for (int j = 0; j < 4; ++j) {
      const int n = n0 + (wn << 6) + (j << 4) + lr;
      const float bs = bias[n];
#pragma unroll
      for (int r = 0; r < 4; ++r) {
        const int m = m0 + (wm << 6) + (i << 4) + (g << 2) + r;
        outf[((size_t)m << 10) + n] =
            acc[i][j][r] + bs + resid[((size_t)m << 10) + n];
      }
    }
  }
}

// ---------------------------------------------------------------------------
// K4: row LayerNorm — one WAVE per row (grid 1024 x 4 rows/block).
// Pure shfl reduction: no LDS, no __syncthreads.
// ---------------------------------------------------------------------------
__global__ __launch_bounds__(256) void layernorm_kernel(
    const float* __restrict__ x, const float* __restrict__ gamma,
    const float* __restrict__ beta, float* __restrict__ out) {
  const int row = (blockIdx.x << 2) + (threadIdx.x >> 6);
  const int lane = threadIdx.x & 63;
  const float* xr = x + ((size_t)row << 10);
  float4 v[4];
  float s1 = 0.f, s2 = 0.f;
#pragma unroll
  for (int i = 0; i < 4; ++i) {
    v[i] = *reinterpret_cast<const float4*>(xr + ((i << 6) + lane) * 4);
    s1 += v[i].x + v[i].y + v[i].z + v[i].w;
    s2 += v[i].x * v[i].x + v[i].y * v[i].y + v[i].z * v[i].z + v[i].w * v[i].w;
  }
#pragma unroll
  for (int off = 1; off < 64; off <<= 1) {
    s1 += __shfl_xor(s1, off);
    s2 += __shfl_xor(s2, off);
  }
  const float mu = s1 * (1.0f / 1024.0f);
  const float var = s2 * (1.0f / 1024.0f) - mu * mu;
  const float rs = rsqrtf(var + 1e-5f);
  float* orow = out + ((size_t)row << 10);
#pragma unroll
  for (int i = 0; i < 4; ++i) {
    const int c = ((i << 6) + lane) * 4;
    const float4 gm = *reinterpret_cast<const float4*>(gamma + c);
    const float4 bt = *reinterpret_cast<const float4*>(beta + c);
    float4 o;
    o.x = (v[i].x - mu) * rs * gm.x + bt.x;
    o.y = (v[i].y - mu) * rs * gm.y + bt.y;
    o.z = (v[i].z - mu) * rs * gm.z + bt.z;
    o.w = (v[i].w - mu) * rs * gm.w + bt.w;
    *reinterpret_cast<float4*>(orow + c) = o;
  }
}

// ---------------------------------------------------------------------------
// workspace layout (bytes)
// ---------------------------------------------------------------------------
static constexpr size_t OFF_QB = 0;          // 8 MiB  bf16 q   [b,h,s,dk]
static constexpr size_t OFF_KB = 8388608;    // 8 MiB  bf16 k'  [b,h,s,dk]
static constexpr size_t OFF_VP = 16777216;   // 8 MiB  bf16 v' key-tiled
static constexpr size_t OFF_WT = 25165824;   // 4 x 2 MiB bf16 W^T (q,k,v,o)
static constexpr size_t OFF_CTX = 33554432;  // 8 MiB  bf16 ctx
static constexpr size_t OFF_LN = 41943040;   // 16 MiB fp32 pre-LN

extern "C" void kernel_launch(void* const* d_in, const int* in_sizes, int n_in,
                              void* d_out, int out_size, void* d_ws, size_t ws_size,
                              hipStream_t stream) {
  (void)in_sizes; (void)n_in; (void)out_size; (void)ws_size;
  const float* Q = (const float*)d_in[0];
  const float* K = (const float*)d_in[1];
  const float* V = (const float*)d_in[2];
  const float* Wq = (const float*)d_in[3];
  const float* bq = (const float*)d_in[4];
  const float* Wk = (const float*)d_in[5];
  const float* bk = (const float*)d_in[6];
  const float* Wv = (const float*)d_in[7];
  const float* bv = (const float*)d_in[8];
  const float* Wo = (const float*)d_in[9];
  const float* bo = (const float*)d_in[10];
  const float* pos_k = (const float*)d_in[11];
  const float* pos_v = (const float*)d_in[12];
  const float* gamma = (const float*)d_in[13];
  const float* beta = (const float*)d_in[14];

  char* ws = (char*)d_ws;
  unsigned short* qb = (unsigned short*)(ws + OFF_QB);
  unsigned short* kb = (unsigned short*)(ws + OFF_KB);
  unsigned short* vP = (unsigned short*)(ws + OFF_VP);
  unsigned short* wt = (unsigned short*)(ws + OFF_WT);
  unsigned short* ctxb = (unsigned short*)(ws + OFF_CTX);
  float* lnb = (float*)(ws + OFF_LN);

  float* outF = (float*)d_out;
  float* attnF = outF + 4194304;  // attn region: [B,H,S,S]

  transpose_w<<<dim3(16, 16, 4), 256, 0, stream>>>(Wq, Wk, Wv, Wo, wt);
  gemm_qkv<<<dim3(8, 32, 3), 256, 0, stream>>>(Q, K, V, wt, bq, bk, bv,
                                               pos_k, pos_v, qb, kb, vP);
  attn_fused<<<dim3(1024), 256, 0, stream>>>(qb, kb, vP, ctxb, attnF);
  gemm_out<<<dim3(8, 32), 256, 0, stream>>>(ctxb, wt + 3145728, bo, Q, lnb);
  layernorm_kernel<<<1024, 256, 0, stream>>>(lnb, gamma, beta, outF);
}

// Round 17
// 193.435 us; speedup vs baseline: 1.0440x; 1.0440x over previous
//
#include <hip/hip_runtime.h>
#include <cstdint>
#include <cstddef>

// ---------------------------------------------------------------------------
// MultiHeadAttention block, MI355X/gfx950.  Round 17 (final) = R15-exact.
// B=4, S=1024, D=1024, H=16, DK=DV=64.  Outputs (out[B,S,D], attn[B,H,S,S]) fp32.
// Best-known-good: R10 pipeline (194.8us) + 1-wave-per-row LN (R15: 195.8us).
// R16's setprio regressed (−6us, lockstep-barrier regime) — removed.
// ---------------------------------------------------------------------------

typedef __attribute__((ext_vector_type(8))) short short8;   // 8 x bf16 (4 VGPR)
typedef __attribute__((ext_vector_type(4))) short short4v;  // 8B vector
typedef __attribute__((ext_vector_type(4))) float f32x4;    // MFMA accum

typedef __attribute__((address_space(1))) void gl_void;
typedef __attribute__((address_space(3))) void lds_void;

#define MFMA16(a, b, c) __builtin_amdgcn_mfma_f32_16x16x32_bf16(a, b, c, 0, 0, 0)
#define GLL(src, dst) __builtin_amdgcn_global_load_lds((gl_void*)(src), (lds_void*)(dst), 16, 0, 0)
#define SBAR() __builtin_amdgcn_s_barrier()
// counted wait, memory clobber only (no sched_barrier: R6 regression)
#define WAIT_VM(n) asm volatile("s_waitcnt vmcnt(" #n ")" ::: "memory")

__device__ __forceinline__ unsigned short f2bf(float f) {
  union { float f; unsigned u; } v; v.f = f;
  unsigned r = v.u + 0x7FFFu + ((v.u >> 16) & 1u);  // RNE
  return (unsigned short)(r >> 16);
}
__device__ __forceinline__ float bf2f(unsigned short h) {
  union { unsigned u; float f; } v; v.u = ((unsigned)h) << 16;
  return v.f;
}

// ---------------------------------------------------------------------------
// K0: transpose-convert 1024x1024 fp32 W -> bf16 W^T (N x K), z selects W
// ---------------------------------------------------------------------------
__global__ __launch_bounds__(256) void transpose_w(
    const float* __restrict__ wq, const float* __restrict__ wk,
    const float* __restrict__ wv, const float* __restrict__ wo,
    unsigned short* __restrict__ wt) {
  __shared__ unsigned short tile[64][68];
  const int z = blockIdx.z;
  const float* W = (z == 0) ? wq : (z == 1) ? wk : (z == 2) ? wv : wo;
  unsigned short* out = wt + (size_t)z * 1048576;
  const int n0 = blockIdx.x * 64, k0 = blockIdx.y * 64;
  const int tr = threadIdx.x >> 4;
  const int tc = (threadIdx.x & 15) * 4;
#pragma unroll
  for (int i = 0; i < 4; ++i) {
    int k = tr + i * 16;
    float4 x = *reinterpret_cast<const float4*>(W + (size_t)(k0 + k) * 1024 + n0 + tc);
    tile[k][tc + 0] = f2bf(x.x); tile[k][tc + 1] = f2bf(x.y);
    tile[k][tc + 2] = f2bf(x.z); tile[k][tc + 3] = f2bf(x.w);
  }
  __syncthreads();
#pragma unroll
  for (int i = 0; i < 4; ++i) {
    int n = tr + i * 16;
    short4v o;
    o[0] = (short)tile[tc + 0][n]; o[1] = (short)tile[tc + 1][n];
    o[2] = (short)tile[tc + 2][n]; o[3] = (short)tile[tc + 3][n];
    *reinterpret_cast<short4v*>(out + (size_t)(n0 + n) * 1024 + k0 + tc) = o;
  }
}

// ---------------------------------------------------------------------------
// K1: fused QKV projection GEMM, R4 2-phase structure (__syncthreads).
// z==0: q=(acc+bias)*0.125*log2e -> qb ; z==1: +pos_k -> kb ;
// z==2: +pos_v -> vP key-tiled [bh][s>>3][dv][s&7].
// ---------------------------------------------------------------------------
__global__ __launch_bounds__(256) void gemm_qkv(
    const float* __restrict__ Qf, const float* __restrict__ Kf,
    const float* __restrict__ Vf, const unsigned short* __restrict__ wt,
    const float* __restrict__ bq, const float* __restrict__ bk,
    const float* __restrict__ bv, const float* __restrict__ pos_k,
    const float* __restrict__ pos_v, unsigned short* __restrict__ qb,
    unsigned short* __restrict__ kbuf, unsigned short* __restrict__ vP) {
  __shared__ unsigned short lds[16384];  // A dbuf [0,16K) | B dbuf [16K,32K)
  const int z = blockIdx.z;
  const float* A = (z == 0) ? Qf : (z == 1) ? Kf : Vf;
  const unsigned short* Bt = wt + (size_t)z * 1048576;
  const float* bias = (z == 0) ? bq : (z == 1) ? bk : bv;

  const int tid = threadIdx.x;
  const int lane = tid & 63;
  const int w = tid >> 6;
  const int g = lane >> 4;
  const int lr = lane & 15;
  const int wg = blockIdx.y * 8 + blockIdx.x;
  const int lg = (wg & 7) * 32 + (wg >> 3);
  const int m0 = (lg >> 3) << 7;
  const int n0 = (lg & 7) << 7;
  const int wm = w >> 1, wn = w & 1;

  const int ra0 = tid >> 2, ca = tid & 3;
  const int ra1 = ra0 + 64;
  const int wA0 = ra0 * 64 + ((ca ^ ((ra0 >> 1) & 3)) << 4);
  const int wA1 = ra1 * 64 + ((ca ^ ((ra1 >> 1) & 3)) << 4);
  const float* a0p = A + (size_t)(m0 + ra0) * 1024 + ca * 8;
  const float* a1p = A + (size_t)(m0 + ra1) * 1024 + ca * 8;

  const int c0 = (w << 6) + lane;
  const int r0 = c0 >> 2;
  const int sl0 = (c0 & 3) ^ ((r0 >> 1) & 3);
  const int c1 = c0 + 256;
  const int r1 = c1 >> 2;
  const int sl1 = (c1 & 3) ^ ((r1 >> 1) & 3);
  const size_t gb0 = ((size_t)(n0 + r0) << 10) + (sl0 << 3);
  const size_t gb1 = ((size_t)(n0 + r1) << 10) + (sl1 << 3);
  char* ldsc = (char*)lds;

  int offA[4], offB[4];
#pragma unroll
  for (int i = 0; i < 4; ++i) {
    int rt = (wm << 6) + (i << 4) + lr;
    offA[i] = rt * 64 + ((g ^ ((rt >> 1) & 3)) << 4);
    int nt = (wn << 6) + (i << 4) + lr;
    offB[i] = nt * 64 + ((g ^ ((nt >> 1) & 3)) << 4);
  }

  f32x4 acc[4][4] = {};

  // prologue: stage kt=0 into buffer 0
  {
    const float4 fa = *reinterpret_cast<const float4*>(a0p);
    const float4 fb = *reinterpret_cast<const float4*>(a0p + 4);
    const float4 fc = *reinterpret_cast<const float4*>(a1p);
    const float4 fd = *reinterpret_cast<const float4*>(a1p + 4);
    short8 pa, pb;
    pa[0] = (short)f2bf(fa.x); pa[1] = (short)f2bf(fa.y);
    pa[2] = (short)f2bf(fa.z); pa[3] = (short)f2bf(fa.w);
    pa[4] = (short)f2bf(fb.x); pa[5] = (short)f2bf(fb.y);
    pa[6] = (short)f2bf(fb.z); pa[7] = (short)f2bf(fb.w);
    pb[0] = (short)f2bf(fc.x); pb[1] = (short)f2bf(fc.y);
    pb[2] = (short)f2bf(fc.z); pb[3] = (short)f2bf(fc.w);
    pb[4] = (short)f2bf(fd.x); pb[5] = (short)f2bf(fd.y);
    pb[6] = (short)f2bf(fd.z); pb[7] = (short)f2bf(fd.w);
    *reinterpret_cast<short8*>(ldsc + wA0) = pa;
    *reinterpret_cast<short8*>(ldsc + wA1) = pb;
    __builtin_amdgcn_global_load_lds((gl_void*)(Bt + gb0),
                                     (lds_void*)(ldsc + 16384 + (w << 10)), 16, 0, 0);
    __builtin_amdgcn_global_load_lds((gl_void*)(Bt + gb1),
                                     (lds_void*)(ldsc + 16384 + 4096 + (w << 10)), 16, 0, 0);
    __syncthreads();
  }

  for (int kt = 0; kt < 32; ++kt) {
    const int cur = (kt & 1) << 13;
    const int nxt = ((kt + 1) & 1) << 13;
    float4 fa, fb, fc, fd;
    if (kt < 31) {
      const int kb32 = (kt + 1) << 5;
      __builtin_amdgcn_global_load_lds((gl_void*)(Bt + gb0 + kb32),
                                       (lds_void*)(ldsc + 16384 + nxt + (w << 10)), 16, 0, 0);
      __builtin_amdgcn_global_load_lds((gl_void*)(Bt + gb1 + kb32),
                                       (lds_void*)(ldsc + 16384 + nxt + 4096 + (w << 10)), 16, 0, 0);
      fa = *reinterpret_cast<const float4*>(a0p + kb32);
      fb = *reinterpret_cast<const float4*>(a0p + kb32 + 4);
      fc = *reinterpret_cast<const float4*>(a1p + kb32);
      fd = *reinterpret_cast<const float4*>(a1p + kb32 + 4);
    }
    short8 am[4], bn[4];
#pragma unroll
    for (int i = 0; i < 4; ++i) {
      am[i] = *reinterpret_cast<const short8*>(ldsc + cur + offA[i]);
      bn[i] = *reinterpret_cast<const short8*>(ldsc + 16384 + cur + offB[i]);
    }
#pragma unroll
    for (int i = 0; i < 4; ++i)
#pragma unroll
      for (int j = 0; j < 4; ++j)
        acc[i][j] = MFMA16(am[i], bn[j], acc[i][j]);
    if (kt < 31) {
      short8 pa, pb;
      pa[0] = (short)f2bf(fa.x); pa[1] = (short)f2bf(fa.y);
      pa[2] = (short)f2bf(fa.z); pa[3] = (short)f2bf(fa.w);
      pa[4] = (short)f2bf(fb.x); pa[5] = (short)f2bf(fb.y);
      pa[6] = (short)f2bf(fb.z); pa[7] = (short)f2bf(fb.w);
      pb[0] = (short)f2bf(fc.x); pb[1] = (short)f2bf(fc.y);
      pb[2] = (short)f2bf(fc.z); pb[3] = (short)f2bf(fc.w);
      pb[4] = (short)f2bf(fd.x); pb[5] = (short)f2bf(fd.y);
      pb[6] = (short)f2bf(fd.z); pb[7] = (short)f2bf(fd.w);
      *reinterpret_cast<short8*>(ldsc + nxt + wA0) = pa;
      *reinterpret_cast<short8*>(ldsc + nxt + wA1) = pb;
    }
    __syncthreads();
  }

#pragma unroll
  for (int i = 0; i < 4; ++i) {
#pragma unroll
    for (int j = 0; j < 4; ++j) {
      const int n = n0 + (wn << 6) + (j << 4) + lr;
      const int hh = n >> 6, dk = n & 63;
      const float bs = bias[n];
      const int mb = m0 + (wm << 6) + (i << 4) + (g << 2);
      const int b = mb >> 10, s0 = mb & 1023;
      if (z == 2) {
        short4v o;
#pragma unroll
        for (int r = 0; r < 4; ++r) {
          const float val = acc[i][j][r] + bs +
                            pos_v[((((size_t)hh << 10) + s0 + r) << 6) + dk];
          o[r] = (short)f2bf(val);
        }
        // vP[bh][s>>3][dv][s&7]: elem off = (s>>3)*512 + dv*8 + (s&7).
        *reinterpret_cast<short4v*>(
            vP + ((size_t)(b * 16 + hh) << 16) + ((s0 >> 3) << 9) + (dk << 3) +
            (s0 & 7)) = o;
      } else {
#pragma unroll
        for (int r = 0; r < 4; ++r) {
          float val = acc[i][j][r];
          if (z == 0) {
            val = (val + bs) * 0.180336880111f;  // 0.125 * log2(e): exp2 fold
          } else {
            val = val + bs + pos_k[((((size_t)hh << 10) + s0 + r) << 6) + dk];
          }
          unsigned short* dst = (z == 0) ? qb : kbuf;
          dst[((((size_t)(b * 16 + hh) << 10) + s0 + r) << 6) + dk] = f2bf(val);
        }
      }
    }
  }
}

// ---------------------------------------------------------------------------
// K2: FUSED attention — R10-EXACT.  4 waves x 16 q-rows, grid 1024
// (XCD-swizzled).  LDS 24KB: K dbuf 16K | p-tiles 4 x 2K.  V direct from
// key-tiled vP (L2-resident).
// pass0 vmcnt: K(ct+1)[2 glls] -> vmcnt(2); tail 0.
// pass1 vmcnt: ct=0 -> 2, steady -> 12, ct=15 -> 10.
// ---------------------------------------------------------------------------
__global__ __launch_bounds__(256) void attn_fused(
    const unsigned short* __restrict__ qb,
    const unsigned short* __restrict__ kb,
    const unsigned short* __restrict__ vP,
    unsigned short* __restrict__ ctxb,
    float* __restrict__ attn_out) {
  __shared__ char smem[24576];  // K dbuf 16K | p-tiles 4 x 2K
  const int tid = threadIdx.x;
  const int lane = tid & 63;
  const int w = tid >> 6;
  const int g = lane >> 4;
  const int lr = lane & 15;
  const int wg = ((blockIdx.x & 7) << 7) + (blockIdx.x >> 3);
  const int bh = wg >> 4, qt = wg & 15;
  const int b = bh >> 4, h = bh & 15;
  const int qrow0 = (qt << 6) + (w << 4);
  const size_t headoff = (size_t)bh << 16;

  const size_t qoff = headoff + (size_t)(qrow0 + lr) * 64 + (g << 3);
  const short8 a0 = *reinterpret_cast<const short8*>(qb + qoff);
  const short8 a1 = *reinterpret_cast<const short8*>(qb + qoff + 32);

  const int key0 = tid >> 3, sl0 = (tid & 7) ^ (key0 & 7);
  const int key1 = 32 + (tid >> 3), sl1 = (tid & 7) ^ (key1 & 7);
  const unsigned short* ks0 = kb + headoff + (size_t)key0 * 64 + (sl0 << 3);
  const unsigned short* ks1 = kb + headoff + (size_t)key1 * 64 + (sl1 << 3);

  // ================= pass 0: row sums =================
  GLL(ks0, smem + (w << 10));                   // K(0) -> b0
  GLL(ks1, smem + 4096 + (w << 10));
  GLL(ks0 + 4096, smem + 8192 + (w << 10));     // K(1) -> b1
  GLL(ks1 + 4096, smem + 8192 + 4096 + (w << 10));

  float l[4] = {0.f, 0.f, 0.f, 0.f};
  for (int ct = 0; ct < 16; ++ct) {
    if (ct < 15) { WAIT_VM(2); } else { WAIT_VM(0); }
    SBAR();
    const char* kl = smem + ((ct & 1) << 13);
#pragma unroll
    for (int kf = 0; kf < 4; ++kf) {
      const int kr = (kf << 4) + lr;
      const char* row = kl + (kr << 7);
      const short8 b0 = *reinterpret_cast<const short8*>(row + ((g ^ (kr & 7)) << 4));
      const short8 b1 = *reinterpret_cast<const short8*>(row + (((4 + g) ^ (kr & 7)) << 4));
      f32x4 acc = {0.f, 0.f, 0.f, 0.f};
      acc = MFMA16(a0, b0, acc);
      acc = MFMA16(a1, b1, acc);
#pragma unroll
      for (int r = 0; r < 4; ++r) l[r] += exp2f(acc[r]);
    }
    SBAR();
    if (ct + 2 < 16) {
      const int koff = (ct + 2) << 12;
      const int bo = (ct & 1) << 13;
      GLL(ks0 + koff, smem + bo + (w << 10));
      GLL(ks1 + koff, smem + bo + 4096 + (w << 10));
    }
  }
#pragma unroll
  for (int r = 0; r < 4; ++r) {
    l[r] += __shfl_xor(l[r], 1);
    l[r] += __shfl_xor(l[r], 2);
    l[r] += __shfl_xor(l[r], 4);
    l[r] += __shfl_xor(l[r], 8);
  }
  float inv[4];
#pragma unroll
  for (int r = 0; r < 4; ++r) inv[r] = 1.0f / l[r];

  // ================= pass 1: normalized PV + attn write =================
  GLL(ks0, smem + (w << 10));                           // K(0) -> buf0
  GLL(ks1, smem + 4096 + (w << 10));
  GLL(ks0 + 4096, smem + 8192 + (w << 10));             // K(1) -> buf1
  GLL(ks1 + 4096, smem + 8192 + 4096 + (w << 10));

  char* ew = smem + 16384 + (w << 11);  // per-wave 16 x 64 bf16 p-tile
  float* ab = attn_out + ((size_t)bh << 20);
  f32x4 ctx[4] = {};

  for (int ct = 0; ct < 16; ++ct) {
    if (ct == 0) { WAIT_VM(2); }
    else if (ct == 15) { WAIT_VM(10); }
    else { WAIT_VM(12); }
    SBAR();
    const int cur = (ct & 1) << 13;
    const int kc0 = ct << 6;
    const char* kl = smem + cur;

    // QK -> p (normalized, bf16 into wave-private swizzled tile)
#pragma unroll
    for (int kf = 0; kf < 4; ++kf) {
      const int kr = (kf << 4) + lr;
      const char* row = kl + (kr << 7);
      const short8 b0 = *reinterpret_cast<const short8*>(row + ((g ^ (kr & 7)) << 4));
      const short8 b1 = *reinterpret_cast<const short8*>(row + (((4 + g) ^ (kr & 7)) << 4));
      f32x4 acc = {0.f, 0.f, 0.f, 0.f};
      acc = MFMA16(a0, b0, acc);
      acc = MFMA16(a1, b1, acc);
#pragma unroll
      for (int r = 0; r < 4; ++r) {
        const float p = exp2f(acc[r]) * inv[r];
        const int prow = (g << 2) + r;
        const int kc = (kf << 4) + lr;
        *(unsigned short*)(ew + (prow << 7) + ((((kc >> 3) ^ (prow & 7))) << 4) +
                           ((kc & 7) << 1)) = f2bf(p);
      }
    }

    // normalized attn chunk write: wave's 16 rows x 64 keys fp32 (R10-exact)
#pragma unroll
    for (int p2 = 0; p2 < 2; ++p2) {
      const int row = lane >> 2;
      const int s = (lane & 3) + (p2 << 2);
      const short8 pv = *reinterpret_cast<const short8*>(
          ew + (row << 7) + ((s ^ (row & 7)) << 4));
      float* dst = ab + ((size_t)(qrow0 + row) << 10) + kc0 + (s << 3);
      float4 o0, o1;
      o0.x = bf2f((unsigned short)pv[0]); o0.y = bf2f((unsigned short)pv[1]);
      o0.z = bf2f((unsigned short)pv[2]); o0.w = bf2f((unsigned short)pv[3]);
      o1.x = bf2f((unsigned short)pv[4]); o1.y = bf2f((unsigned short)pv[5]);
      o1.z = bf2f((unsigned short)pv[6]); o1.w = bf2f((unsigned short)pv[7]);
      *reinterpret_cast<float4*>(dst) = o0;
      *reinterpret_cast<float4*>(dst + 4) = o1;
    }

    // PV with direct V loads from key-tiled vP (L2-resident)
    const short8 pa0 = *reinterpret_cast<const short8*>(
        ew + (lr << 7) + ((g ^ (lr & 7)) << 4));
    const short8 pa1 = *reinterpret_cast<const short8*>(
        ew + (lr << 7) + (((4 + g) ^ (lr & 7)) << 4));
    const unsigned short* vch0 = vP + headoff + ((size_t)((kc0 >> 3) + g) << 9);
    const unsigned short* vch1 = vch0 + (4 << 9);
#pragma unroll
    for (int dt = 0; dt < 4; ++dt) {
      const int dv = (dt << 4) + lr;
      const short8 v0 = *reinterpret_cast<const short8*>(vch0 + (dv << 3));
      const short8 v1 = *reinterpret_cast<const short8*>(vch1 + (dv << 3));
      ctx[dt] = MFMA16(pa0, v0, ctx[dt]);
      ctx[dt] = MFMA16(pa1, v1, ctx[dt]);
    }
    SBAR();
    if (ct + 2 < 16) {
      const int kn = (ct + 2) << 6;
      const int bo = (ct & 1) << 13;
      GLL(ks0 + ((size_t)kn << 6), smem + bo + (w << 10));
      GLL(ks1 + ((size_t)kn << 6), smem + bo + 4096 + (w << 10));
    }
  }

  // ctx write (already normalized), layout [b*S+s][h*64+dv]
#pragma unroll
  for (int dt = 0; dt < 4; ++dt) {
#pragma unroll
    for (int r = 0; r < 4; ++r) {
      const int srow = qrow0 + (g << 2) + r;
      const int n = (h << 6) + (dt << 4) + lr;
      ctxb[((((size_t)(b << 10)) + srow) << 10) + n] = f2bf(ctx[dt][r]);
    }
  }
}

// ---------------------------------------------------------------------------
// K3: out-projection GEMM, R4 2-phase structure (__syncthreads).
// ---------------------------------------------------------------------------
__global__ __launch_bounds__(256) void gemm_out(
    const unsigned short* __restrict__ A, const unsigned short* __restrict__ Bt,
    const float* __restrict__ bias, const float* __restrict__ resid,
    float* __restrict__ outf) {
  __shared__ unsigned short lds[16384];
  const int tid = threadIdx.x;
  const int lane = tid & 63;
  const int w = tid >> 6;
  const int g = lane >> 4;
  const int lr = lane & 15;
  const int wg = blockIdx.y * 8 + blockIdx.x;
  const int lg = (wg & 7) * 32 + (wg >> 3);
  const int m0 = (lg >> 3) << 7;
  const int n0 = (lg & 7) << 7;
  const int wm = w >> 1, wn = w & 1;

  const int c0 = (w << 6) + lane;
  const int r0 = c0 >> 2;
  const int sl0 = (c0 & 3) ^ ((r0 >> 1) & 3);
  const int c1 = c0 + 256;
  const int r1 = c1 >> 2;
  const int sl1 = (c1 & 3) ^ ((r1 >> 1) & 3);

  const size_t ga0 = ((size_t)(m0 + r0) << 10) + (sl0 << 3);
  const size_t ga1 = ((size_t)(m0 + r1) << 10) + (sl1 << 3);
  const size_t gb0 = ((size_t)(n0 + r0) << 10) + (sl0 << 3);
  const size_t gb1 = ((size_t)(n0 + r1) << 10) + (sl1 << 3);

  char* ldsc = (char*)lds;

  int offA[4], offB[4];
#pragma unroll
  for (int i = 0; i < 4; ++i) {
    int rt = (wm << 6) + (i << 4) + lr;
    offA[i] = rt * 64 + ((g ^ ((rt >> 1) & 3)) << 4);
    int nt = (wn << 6) + (i << 4) + lr;
    offB[i] = nt * 64 + ((g ^ ((nt >> 1) & 3)) << 4);
  }

  // prologue: stage kt=0 into buffer 0
  GLL(A + ga0, ldsc + (w << 10));
  GLL(A + ga1, ldsc + 4096 + (w << 10));
  GLL(Bt + gb0, ldsc + 16384 + (w << 10));
  GLL(Bt + gb1, ldsc + 16384 + 4096 + (w << 10));
  __syncthreads();

  f32x4 acc[4][4] = {};
  for (int kt = 0; kt < 32; ++kt) {
    const int cur = (kt & 1) << 13;
    if (kt < 31) {
      const int nxt = ((kt + 1) & 1) << 13;
      const int kb32 = (kt + 1) << 5;
      GLL(A + ga0 + kb32, ldsc + nxt + (w << 10));
      GLL(A + ga1 + kb32, ldsc + nxt + 4096 + (w << 10));
      GLL(Bt + gb0 + kb32, ldsc + 16384 + nxt + (w << 10));
      GLL(Bt + gb1 + kb32, ldsc + 16384 + nxt + 4096 + (w << 10));
    }
    short8 am[4], bn[4];
#pragma unroll
    for (int i = 0; i < 4; ++i) {
      am[i] = *reinterpret_cast<const short8*>(ldsc + cur + offA[i]);
      bn[i] = *reinterpret_cast<const short8*>(ldsc + 16384 + cur + offB[i]);
    }
#pragma unroll
    for (int i = 0; i < 4; ++i)
#pragma unroll
      for (int j = 0; j < 4; ++j)
        acc[i][j] = MFMA16(am[i], bn[j], acc[i][j]);
    __syncthreads();
  }

#pragma unroll
  for (int i = 0; i < 4; ++i) {
#pragma unroll
    for (int j = 0; j < 4; ++j) {
      const int n = n0 + (wn << 6) + (j << 4) + lr;
      const float bs = bias[n];
#pragma unroll
      for (int r = 0; r < 4; ++r) {
        const int m = m0 + (wm << 6) + (i << 4) + (g << 2) + r;
        outf[((size_t)m << 10) + n] =
            acc[i][j][r] + bs + resid[((size_t)m << 10) + n];
      }
    }
  }
}

// ---------------------------------------------------------------------------
// K4: row LayerNorm — one WAVE per row (grid 1024 x 4 rows/block).
// Pure shfl reduction: no LDS, no __syncthreads.
// ---------------------------------------------------------------------------
__global__ __launch_bounds__(256) void layernorm_kernel(
    const float* __restrict__ x, const float* __restrict__ gamma,
    const float* __restrict__ beta, float* __restrict__ out) {
  const int row = (blockIdx.x << 2) + (threadIdx.x >> 6);
  const int lane = threadIdx.x & 63;
  const float* xr = x + ((size_t)row << 10);
  float4 v[4];
  float s1 = 0.f, s2 = 0.f;
#pragma unroll
  for (int i = 0; i < 4; ++i) {
    v[i] = *reinterpret_cast<const float4*>(xr + ((i << 6) + lane) * 4);
    s1 += v[i].x + v[i].y + v[i].z + v[i].w;
    s2 += v[i].x * v[i].x + v[i].y * v[i].y + v[i].z * v[i].z + v[i].w * v[i].w;
  }
#pragma unroll
  for (int off = 1; off < 64; off <<= 1) {
    s1 += __shfl_xor(s1, off);
    s2 += __shfl_xor(s2, off);
  }
  const float mu = s1 * (1.0f / 1024.0f);
  const float var = s2 * (1.0f / 1024.0f) - mu * mu;
  const float rs = rsqrtf(var + 1e-5f);
  float* orow = out + ((size_t)row << 10);
#pragma unroll
  for (int i = 0; i < 4; ++i) {
    const int c = ((i << 6) + lane) * 4;
    const float4 gm = *reinterpret_cast<const float4*>(gamma + c);
    const float4 bt = *reinterpret_cast<const float4*>(beta + c);
    float4 o;
    o.x = (v[i].x - mu) * rs * gm.x + bt.x;
    o.y = (v[i].y - mu) * rs * gm.y + bt.y;
    o.z = (v[i].z - mu) * rs * gm.z + bt.z;
    o.w = (v[i].w - mu) * rs * gm.w + bt.w;
    *reinterpret_cast<float4*>(orow + c) = o;
  }
}

// ---------------------------------------------------------------------------
// workspace layout (bytes)
// ---------------------------------------------------------------------------
static constexpr size_t OFF_QB = 0;          // 8 MiB  bf16 q   [b,h,s,dk]
static constexpr size_t OFF_KB = 8388608;    // 8 MiB  bf16 k'  [b,h,s,dk]
static constexpr size_t OFF_VP = 16777216;   // 8 MiB  bf16 v' key-tiled
static constexpr size_t OFF_WT = 25165824;   // 4 x 2 MiB bf16 W^T (q,k,v,o)
static constexpr size_t OFF_CTX = 33554432;  // 8 MiB  bf16 ctx
static constexpr size_t OFF_LN = 41943040;   // 16 MiB fp32 pre-LN

extern "C" void kernel_launch(void* const* d_in, const int* in_sizes, int n_in,
                              void* d_out, int out_size, void* d_ws, size_t ws_size,
                              hipStream_t stream) {
  (void)in_sizes; (void)n_in; (void)out_size; (void)ws_size;
  const float* Q = (const float*)d_in[0];
  const float* K = (const float*)d_in[1];
  const float* V = (const float*)d_in[2];
  const float* Wq = (const float*)d_in[3];
  const float* bq = (const float*)d_in[4];
  const float* Wk = (const float*)d_in[5];
  const float* bk = (const float*)d_in[6];
  const float* Wv = (const float*)d_in[7];
  const float* bv = (const float*)d_in[8];
  const float* Wo = (const float*)d_in[9];
  const float* bo = (const float*)d_in[10];
  const float* pos_k = (const float*)d_in[11];
  const float* pos_v = (const float*)d_in[12];
  const float* gamma = (const float*)d_in[13];
  const float* beta = (const float*)d_in[14];

  char* ws = (char*)d_ws;
  unsigned short* qb = (unsigned short*)(ws + OFF_QB);
  unsigned short* kb = (unsigned short*)(ws + OFF_KB);
  unsigned short* vP = (unsigned short*)(ws + OFF_VP);
  unsigned short* wt = (unsigned short*)(ws + OFF_WT);
  unsigned short* ctxb = (unsigned short*)(ws + OFF_CTX);
  float* lnb = (float*)(ws + OFF_LN);

  float* outF = (float*)d_out;
  float* attnF = outF + 4194304;  // attn region: [B,H,S,S]

  transpose_w<<<dim3(16, 16, 4), 256, 0, stream>>>(Wq, Wk, Wv, Wo, wt);
  gemm_qkv<<<dim3(8, 32, 3), 256, 0, stream>>>(Q, K, V, wt, bq, bk, bv,
                                               pos_k, pos_v, qb, kb, vP);
  attn_fused<<<dim3(1024), 256, 0, stream>>>(qb, kb, vP, ctxb, attnF);
  gemm_out<<<dim3(8, 32), 256, 0, stream>>>(ctxb, wt + 3145728, bo, Q, lnb);
  layernorm_kernel<<<1024, 256, 0, stream>>>(lnb, gamma, beta, outF);
}